// Round 3
// baseline (118.761 us; speedup 1.0000x reference)
//
#include <hip/hip_runtime.h>
#include <hip/hip_bf16.h>

#define BLOCK 256
#define IPT   2                 // i-values per thread
#define JS    128               // j-slice per block
#define ITILE (BLOCK * IPT)     // 512 = i-superblock height
#define JT_PER_I (ITILE / JS)   // 4 j-tiles per i-superblock
#define NACC  64                // spread accumulator slots (cuts same-address atomic serialization)

// M_ij = clip(p_i-p_j)*clip(t_i-t_j) is symmetric. Superblocks of ITILE rows:
// tiles strictly below the diagonal band get weight 2, diagonal-band tiles
// weight 1 (computed whole, no per-pair predicate). loss = 1 - S/(n*(n-1)).
__global__ __launch_bounds__(BLOCK) void kendall_fused(
    const float* __restrict__ p, const float* __restrict__ t,
    float* __restrict__ acc, unsigned int* __restrict__ cnt,
    float* __restrict__ out, int n, unsigned int nWorking) {
    const int bi = blockIdx.x;                   // i-superblock (0..31)
    const int bj = blockIdx.y;                   // j-tile (0..127)
    if (bj >= (bi + 1) * JT_PER_I) return;       // mirror covered by symmetry
    const float w = (bj < bi * JT_PER_I) ? 2.0f : 1.0f;

    __shared__ float2 sjt[JS];                   // interleaved (p_j, t_j) -> float4 = 2 j's
    __shared__ float wsum[BLOCK / 64];

    const int i0 = bi * ITILE;
    const int j0 = bj * JS;

    for (int k = threadIdx.x; k < JS; k += BLOCK) {
        int j = j0 + k;
        float pj = (j < n) ? p[j] : 0.0f;
        float tj = (j < n) ? t[j] : 0.0f;
        sjt[k] = make_float2(pj, tj);            // 8B/lane consecutive: 2-way alias = free
    }

    float2 pit[IPT];
    float ok[IPT];
#pragma unroll
    for (int u = 0; u < IPT; ++u) {
        int i = i0 + u * BLOCK + threadIdx.x;    // coalesced per u
        bool in = (i < n);
        pit[u] = make_float2(in ? p[i] : 0.0f, in ? t[i] : 0.0f);
        ok[u] = in ? 1.0f : 0.0f;                // kills fake OOB-i pairs at the end
    }
    __syncthreads();

    const int jcnt = (j0 + JS <= n) ? JS : (n > j0 ? n - j0 : 0);
    const int g4 = jcnt >> 1;                    // float4 groups (2 j each); n%2==0
    const float4* sj4 = reinterpret_cast<const float4*>(sjt);

    float a[IPT * 2] = {0.0f, 0.0f, 0.0f, 0.0f}; // 4 independent fmac chains

#pragma unroll 4
    for (int g = 0; g < g4; ++g) {
        float4 jv = sj4[g];                      // ds_read_b128, wave-uniform broadcast
#pragma unroll
        for (int u = 0; u < IPT; ++u) {
            float pd0 = __builtin_amdgcn_fmed3f(pit[u].x - jv.x, -1.0f, 1.0f);
            float td0 = __builtin_amdgcn_fmed3f(pit[u].y - jv.y, -1.0f, 1.0f);
            a[2 * u]     = fmaf(pd0, td0, a[2 * u]);
            float pd1 = __builtin_amdgcn_fmed3f(pit[u].x - jv.z, -1.0f, 1.0f);
            float td1 = __builtin_amdgcn_fmed3f(pit[u].y - jv.w, -1.0f, 1.0f);
            a[2 * u + 1] = fmaf(pd1, td1, a[2 * u + 1]);
        }
    }

    float s = 0.0f;
#pragma unroll
    for (int u = 0; u < IPT; ++u) s += ok[u] * (a[2 * u] + a[2 * u + 1]);

#pragma unroll
    for (int off = 32; off > 0; off >>= 1) s += __shfl_down(s, off, 64);

    const int lane = threadIdx.x & 63;
    const int wid  = threadIdx.x >> 6;
    if (lane == 0) wsum[wid] = s;
    __syncthreads();

    if (threadIdx.x == 0) {
        float b = 0.0f;
#pragma unroll
        for (int v2 = 0; v2 < BLOCK / 64; ++v2) b += wsum[v2];
        int slot = (bi * JT_PER_I + bj) & (NACC - 1);   // ~33 blocks/slot
        atomicAdd(&acc[slot], w * b);            // device-scope
        __threadfence();                         // acc-add visible before cnt-add
        unsigned int old = atomicAdd(cnt, 1u);
        if (old == nWorking - 1) {               // last working block finalizes
            __threadfence();
            float S = 0.0f;
#pragma unroll
            for (int k = 0; k < NACC; ++k) S += atomicAdd(&acc[k], 0.0f);
            float denom = (float)n * (float)(n - 1);
            out[0] = 1.0f - S / denom;
        }
    }
}

extern "C" void kernel_launch(void* const* d_in, const int* in_sizes, int n_in,
                              void* d_out, int out_size, void* d_ws, size_t ws_size,
                              hipStream_t stream) {
    const float* predict = (const float*)d_in[0];
    const float* target  = (const float*)d_in[1];
    float* out = (float*)d_out;
    float* acc = (float*)d_ws;                        // ws[0..63]: f32 partial slots
    unsigned int* cnt = (unsigned int*)d_ws + NACC;   // ws[64]: completion counter
    const int n = in_sizes[0];

    // zero slots + counter (ws is re-poisoned 0xAA before every timed launch)
    hipMemsetAsync(d_ws, 0, (NACC + 1) * sizeof(float), stream);

    const int gx = (n + ITILE - 1) / ITILE;  // 32
    const int gy = (n + JS - 1) / JS;        // 128
    unsigned int nWorking = 0;
    for (int bi = 0; bi < gx; ++bi) {
        int cap = (bi + 1) * JT_PER_I;
        nWorking += (unsigned int)((cap < gy) ? cap : gy);
    }

    dim3 grid(gx, gy);
    kendall_fused<<<grid, BLOCK, 0, stream>>>(predict, target, acc, cnt, out, n, nWorking);
}

// Round 4
// 84.260 us; speedup vs baseline: 1.4095x; 1.4095x over previous
//
#include <hip/hip_runtime.h>
#include <hip/hip_bf16.h>

#define BLOCK 256
#define IPT   2                 // i-values per thread
#define JS    128               // j-slice per block
#define ITILE (BLOCK * IPT)     // 512 = i-superblock height
#define JT_PER_I (ITILE / JS)   // 4 j-tiles per i-superblock

// M_ij = clip(p_i-p_j)*clip(t_i-t_j) is symmetric. Superblocks of ITILE rows:
// tiles strictly below the diagonal band get weight 2, diagonal-band tiles
// weight 1 (computed whole, no per-pair predicate). loss = 1 - S/(n*(n-1)).
//
// NO atomics, NO fences: each working block writes its weighted partial to a
// private slot; a separate tiny kernel reduces. (R3 post-mortem: 2112
// __threadfence/block = L2-writeback storm = 2x regression.)
__global__ __launch_bounds__(BLOCK) void kendall_pairs(
    const float* __restrict__ p, const float* __restrict__ t,
    float* __restrict__ partial, int n) {
    const int bi = blockIdx.x;                   // i-superblock (0..31)
    const int bj = blockIdx.y;                   // j-tile (0..127)
    if (bj >= (bi + 1) * JT_PER_I) return;       // mirror covered by symmetry
    const float w = (bj < bi * JT_PER_I) ? 2.0f : 1.0f;
    // slot = sum_{k<bi} JT_PER_I*(k+1) + bj  (JT_PER_I*gx <= gy so no clamp; n=16384)
    const int slot = 2 * bi * (bi + 1) + bj;

    __shared__ float2 sjt[JS];                   // interleaved (p_j, t_j): float4 = 2 j's
    __shared__ float wsum[BLOCK / 64];

    const int i0 = bi * ITILE;
    const int j0 = bj * JS;

    for (int k = threadIdx.x; k < JS; k += BLOCK) {
        int j = j0 + k;
        float pj = (j < n) ? p[j] : 0.0f;
        float tj = (j < n) ? t[j] : 0.0f;
        sjt[k] = make_float2(pj, tj);
    }

    float2 pit[IPT];
    float ok[IPT];
#pragma unroll
    for (int u = 0; u < IPT; ++u) {
        int i = i0 + u * BLOCK + threadIdx.x;    // coalesced per u
        bool in = (i < n);
        pit[u] = make_float2(in ? p[i] : 0.0f, in ? t[i] : 0.0f);
        ok[u] = in ? 1.0f : 0.0f;                // kills fake OOB-i pairs at the end
    }
    __syncthreads();

    const int jcnt = (j0 + JS <= n) ? JS : (n > j0 ? n - j0 : 0);
    const int g4 = jcnt >> 1;                    // float4 groups (2 j's each); n even
    const float4* sj4 = reinterpret_cast<const float4*>(sjt);

    float a[IPT * 2] = {0.0f, 0.0f, 0.0f, 0.0f}; // 4 independent fmac chains

#pragma unroll 4
    for (int g = 0; g < g4; ++g) {
        float4 jv = sj4[g];                      // ds_read_b128, wave-uniform broadcast
#pragma unroll
        for (int u = 0; u < IPT; ++u) {
            float pd0 = __builtin_amdgcn_fmed3f(pit[u].x - jv.x, -1.0f, 1.0f);
            float td0 = __builtin_amdgcn_fmed3f(pit[u].y - jv.y, -1.0f, 1.0f);
            a[2 * u]     = fmaf(pd0, td0, a[2 * u]);
            float pd1 = __builtin_amdgcn_fmed3f(pit[u].x - jv.z, -1.0f, 1.0f);
            float td1 = __builtin_amdgcn_fmed3f(pit[u].y - jv.w, -1.0f, 1.0f);
            a[2 * u + 1] = fmaf(pd1, td1, a[2 * u + 1]);
        }
    }

    float s = 0.0f;
#pragma unroll
    for (int u = 0; u < IPT; ++u) s += ok[u] * (a[2 * u] + a[2 * u + 1]);

#pragma unroll
    for (int off = 32; off > 0; off >>= 1) s += __shfl_down(s, off, 64);

    const int lane = threadIdx.x & 63;
    const int wid  = threadIdx.x >> 6;
    if (lane == 0) wsum[wid] = s;
    __syncthreads();

    if (threadIdx.x == 0) {
        float b = 0.0f;
#pragma unroll
        for (int v2 = 0; v2 < BLOCK / 64; ++v2) b += wsum[v2];
        partial[slot] = w * b;                   // private slot: plain store, no atomic
    }
}

// One block: reduce nPartial floats (L2-resident) -> loss.
__global__ __launch_bounds__(BLOCK) void kendall_reduce(
    const float* __restrict__ partial, float* __restrict__ out,
    int nPartial, int n) {
    __shared__ float wsum[BLOCK / 64];
    float s = 0.0f;
    for (int k = threadIdx.x; k < nPartial; k += BLOCK) s += partial[k];
#pragma unroll
    for (int off = 32; off > 0; off >>= 1) s += __shfl_down(s, off, 64);
    const int lane = threadIdx.x & 63;
    const int wid  = threadIdx.x >> 6;
    if (lane == 0) wsum[wid] = s;
    __syncthreads();
    if (threadIdx.x == 0) {
        float S = 0.0f;
#pragma unroll
        for (int v2 = 0; v2 < BLOCK / 64; ++v2) S += wsum[v2];
        float denom = (float)n * (float)(n - 1);
        out[0] = 1.0f - S / denom;
    }
}

extern "C" void kernel_launch(void* const* d_in, const int* in_sizes, int n_in,
                              void* d_out, int out_size, void* d_ws, size_t ws_size,
                              hipStream_t stream) {
    const float* predict = (const float*)d_in[0];
    const float* target  = (const float*)d_in[1];
    float* out = (float*)d_out;
    float* partial = (float*)d_ws;               // 2112 slots, all written each call
    const int n = in_sizes[0];

    const int gx = (n + ITILE - 1) / ITILE;      // 32
    const int gy = (n + JS - 1) / JS;            // 128
    int nWorking = 0;
    for (int bi = 0; bi < gx; ++bi) {
        int cap = (bi + 1) * JT_PER_I;
        nWorking += (cap < gy) ? cap : gy;       // 2112 for n=16384
    }

    dim3 grid(gx, gy);
    kendall_pairs<<<grid, BLOCK, 0, stream>>>(predict, target, partial, n);
    kendall_reduce<<<1, BLOCK, 0, stream>>>(partial, out, nWorking, n);
}